// Round 2
// baseline (239.800 us; speedup 1.0000x reference)
//
#include <hip/hip_runtime.h>

// PermuteWeightSharing: out[row, s*16+k] = x[row, ppos[s]*16+k] - x[row, pneg[s]*16+k]
// row = (b,o,i) flattened, 256 floats per row = 16 slots x 16 floats.
//
// v3: v2 minus nontemporal stores. Round-1 counters showed dispatch time
// tracking a ~1.5 TB/s store-drain rate (131 MB writes / 87 us) -- NT stores
// bypass L2 write-combining and throttle the write path. Plain stores land in
// L2 and drain at full HBM write BW. Keep grid-stride (2048 blocks, 16
// iters/thread, decode amortized) + 4-deep unroll (8 loads in flight).
// All hot-loop indexing in 32-bit (total_v4 = 8.4M << 2^31).

#define NSLOTS 16

typedef float fvec4 __attribute__((ext_vector_type(4)));

__global__ __launch_bounds__(256, 8) void permute_ws_kernel(
    const fvec4* __restrict__ x,
    const float* __restrict__ Ppos,
    const float* __restrict__ Pneg,
    fvec4* __restrict__ out,
    int total_v4)
{
    __shared__ int soff_p[NSLOTS];   // ppos[s] * 4  (float4 units)
    __shared__ int soff_n[NSLOTS];

    const int t = threadIdx.x;
    if (t < NSLOTS) {
        int ip = 0, in_ = 0;
        #pragma unroll
        for (int j = 0; j < NSLOTS; ++j) {
            if (Ppos[t * NSLOTS + j] > 0.5f) ip = j;
            if (Pneg[t * NSLOTS + j] > 0.5f) in_ = j;
        }
        soff_p[t] = ip << 2;
        soff_n[t] = in_ << 2;
    }
    __syncthreads();

    const int idx    = blockIdx.x * blockDim.x + threadIdx.x;
    const int stride = gridDim.x * blockDim.x;   // multiple of 64

    // Within-row geometry is invariant across grid-stride steps (stride % 64 == 0).
    const int v    = idx & 63;    // float4 index within 256-float row
    const int slot = v >> 2;      // [0,16)
    const int k4   = v & 3;       // [0,4)
    // x index = row_base + soff + k4 = (idx - v) + soff + k4 = idx + delta
    const int dp = soff_p[slot] + k4 - v;
    const int dn = soff_n[slot] + k4 - v;

    int i = idx;
    // Main: 4-deep unrolled grid-stride. 8 loads in flight per thread.
    for (; i + 3 * stride < total_v4; i += 4 * stride) {
        const fvec4 a0 = x[i              + dp];
        const fvec4 b0 = x[i              + dn];
        const fvec4 a1 = x[i +     stride + dp];
        const fvec4 b1 = x[i +     stride + dn];
        const fvec4 a2 = x[i + 2 * stride + dp];
        const fvec4 b2 = x[i + 2 * stride + dn];
        const fvec4 a3 = x[i + 3 * stride + dp];
        const fvec4 b3 = x[i + 3 * stride + dn];
        out[i             ] = a0 - b0;
        out[i +     stride] = a1 - b1;
        out[i + 2 * stride] = a2 - b2;
        out[i + 3 * stride] = a3 - b3;
    }
    // Tail (not taken when total_v4 is a multiple of 4*stride).
    for (; i < total_v4; i += stride) {
        const fvec4 a = x[i + dp];
        const fvec4 b = x[i + dn];
        out[i] = a - b;
    }
}

extern "C" void kernel_launch(void* const* d_in, const int* in_sizes, int n_in,
                              void* d_out, int out_size, void* d_ws, size_t ws_size,
                              hipStream_t stream)
{
    const fvec4* x    = (const fvec4*)d_in[0];
    const float* Ppos = (const float*)d_in[1];
    const float* Pneg = (const float*)d_in[2];
    fvec4*       out  = (fvec4*)d_out;

    const int total_v4 = out_size / 4;   // float4 count (33,554,432 / 4 = 8,388,608)

    const int block = 256;
    int blocks_needed = (total_v4 + block - 1) / block;
    // Cap at 2048 blocks (256 CU x 8 blocks/CU) and grid-stride the rest:
    // 16 iterations/thread amortizes the per-block perm decode + sync.
    int grid = blocks_needed > 2048 ? 2048 : blocks_needed;

    permute_ws_kernel<<<grid, block, 0, stream>>>(x, Ppos, Pneg, out, total_v4);
}

// Round 3
// 230.985 us; speedup vs baseline: 1.0382x; 1.0382x over previous
//
#include <hip/hip_runtime.h>

// PermuteWeightSharing: out[row, s*16+k] = x[row, ppos[s]*16+k] - x[row, pneg[s]*16+k]
// row = (b,o,i) flattened, 256 floats per row = 16 slots x 16 floats = 64 float4.
//
// v4: one-shot straight-line (no grid-stride loop). Rounds 1-2 showed the
// grid-stride loop costs ~21 us vs round-0's one-shot (85 vs ~64 us): the
// unrolled loop interleaves loads+stores in one vmcnt queue, so each
// iteration's load-wait also waits behind prior stores (vmcnt counts both,
// in-order) -- loop-carried serialization. Here: each thread handles 4
// independent rows at the same within-row position (dp/dn shared), 8 loads
// issued back-to-back before any wait (4x round-0 MLP), zero loop structure.
// Each wave-load still reads one full permuted 1 KB row (fully coalesced).

#define NSLOTS 16

typedef float fvec4 __attribute__((ext_vector_type(4)));

__global__ __launch_bounds__(256, 8) void permute_ws_kernel(
    const fvec4* __restrict__ x,
    const float* __restrict__ Ppos,
    const float* __restrict__ Pneg,
    fvec4* __restrict__ out,
    int total_v4)
{
    __shared__ int soff_p[NSLOTS];   // ppos[s] * 4  (float4 units)
    __shared__ int soff_n[NSLOTS];

    const int t = threadIdx.x;
    if (t < NSLOTS) {
        int ip = 0, in_ = 0;
        #pragma unroll
        for (int j = 0; j < NSLOTS; ++j) {
            if (Ppos[t * NSLOTS + j] > 0.5f) ip = j;
            if (Pneg[t * NSLOTS + j] > 0.5f) in_ = j;
        }
        soff_p[t] = ip << 2;
        soff_n[t] = in_ << 2;
    }
    __syncthreads();

    // Within-row geometry: v = position within the 64-float4 row.
    const int v    = t & 63;
    const int slot = v >> 2;      // [0,16)
    const int k4   = v & 3;       // [0,4)
    // x index = row_base + soff + k4 = i + (soff + k4 - v)
    const int dp = soff_p[slot] + k4 - v;
    const int dn = soff_n[slot] + k4 - v;

    // Block covers 16 rows = 1024 float4; thread t handles 4 rows at the
    // same position: i0, i0+256, i0+512, i0+768 (row stride 64, 4 rows apart).
    const int i0 = blockIdx.x * 1024 + t;

    if (i0 + 768 < total_v4) {
        // 8 independent loads in flight, then pairwise waits, then 4 stores.
        const fvec4 a0 = x[i0 +   0 + dp];
        const fvec4 b0 = x[i0 +   0 + dn];
        const fvec4 a1 = x[i0 + 256 + dp];
        const fvec4 b1 = x[i0 + 256 + dn];
        const fvec4 a2 = x[i0 + 512 + dp];
        const fvec4 b2 = x[i0 + 512 + dn];
        const fvec4 a3 = x[i0 + 768 + dp];
        const fvec4 b3 = x[i0 + 768 + dn];
        out[i0 +   0] = a0 - b0;
        out[i0 + 256] = a1 - b1;
        out[i0 + 512] = a2 - b2;
        out[i0 + 768] = a3 - b3;
    } else {
        #pragma unroll
        for (int j = 0; j < 4; ++j) {
            const int i = i0 + 256 * j;
            if (i < total_v4) {
                const fvec4 a = x[i + dp];
                const fvec4 b = x[i + dn];
                out[i] = a - b;
            }
        }
    }
}

extern "C" void kernel_launch(void* const* d_in, const int* in_sizes, int n_in,
                              void* d_out, int out_size, void* d_ws, size_t ws_size,
                              hipStream_t stream)
{
    const fvec4* x    = (const fvec4*)d_in[0];
    const float* Ppos = (const float*)d_in[1];
    const float* Pneg = (const float*)d_in[2];
    fvec4*       out  = (fvec4*)d_out;

    const int total_v4 = out_size / 4;   // 33,554,432 / 4 = 8,388,608

    const int block = 256;
    // Each block covers 1024 float4 (16 rows, 4 per thread): 8192 blocks.
    const int grid = (total_v4 + 1023) / 1024;

    permute_ws_kernel<<<grid, block, 0, stream>>>(x, Ppos, Pneg, out, total_v4);
}

// Round 4
// 230.336 us; speedup vs baseline: 1.0411x; 1.0028x over previous
//
#include <hip/hip_runtime.h>

// PermuteWeightSharing: out[row, s*16+k] = x[row, ppos[s]*16+k] - x[row, pneg[s]*16+k]
// row = (b,o,i) flattened, 256 floats per row = 16 slots x 16 floats = 64 float4.
//
// v5: sequential-load + in-wave ds_bpermute permutation.
// Rounds 0-3 all gathered with lane addresses permuted in 64B blocks within
// each 1KB row: the coalescer emits 16 disjoint 64B requests per load instr,
// twice per row (pos+neg). MLP=4 didn't help (round 3) -> request path, not
// latency, is the cap. Here each wave-load reads its row perfectly
// sequentially (lane l -> float4 l of the row); the slot permutation is done
// in-register via ds_bpermute (the permuted element always lives in another
// lane of the same wave, since one wave-position == one row). Per position:
// 1 sequential 16B load, 8 ds_bpermute, 1 sequential 16B store.

#define NSLOTS 16

typedef float fvec4 __attribute__((ext_vector_type(4)));

__device__ inline fvec4 lane_gather(fvec4 a, int byte_addr)
{
    fvec4 r;
    r.x = __int_as_float(__builtin_amdgcn_ds_bpermute(byte_addr, __float_as_int(a.x)));
    r.y = __int_as_float(__builtin_amdgcn_ds_bpermute(byte_addr, __float_as_int(a.y)));
    r.z = __int_as_float(__builtin_amdgcn_ds_bpermute(byte_addr, __float_as_int(a.z)));
    r.w = __int_as_float(__builtin_amdgcn_ds_bpermute(byte_addr, __float_as_int(a.w)));
    return r;
}

__global__ __launch_bounds__(256, 8) void permute_ws_kernel(
    const fvec4* __restrict__ x,
    const float* __restrict__ Ppos,
    const float* __restrict__ Pneg,
    fvec4* __restrict__ out,
    int total_v4)
{
    __shared__ int spos[NSLOTS];
    __shared__ int sneg[NSLOTS];

    const int t = threadIdx.x;
    if (t < NSLOTS) {
        int ip = 0, in_ = 0;
        #pragma unroll
        for (int j = 0; j < NSLOTS; ++j) {
            if (Ppos[t * NSLOTS + j] > 0.5f) ip = j;
            if (Pneg[t * NSLOTS + j] > 0.5f) in_ = j;
        }
        spos[t] = ip;
        sneg[t] = in_;
    }
    __syncthreads();

    // Lane l of each wave holds float4 l of one row (sequential load).
    // Output lane v needs input lane pv = spos[v>>2]*4 + (v&3) of the SAME
    // wave (one wave-position == one 64-float4 row). ds_bpermute byte addr
    // = src_lane * 4.
    const int v  = t & 63;
    const int bp = ((spos[v >> 2] << 2) | (v & 3)) << 2;
    const int bn = ((sneg[v >> 2] << 2) | (v & 3)) << 2;

    // Block covers 16 rows = 1024 float4; thread t handles 4 rows at the
    // same within-row position: i0, i0+256, i0+512, i0+768.
    const int i0 = blockIdx.x * 1024 + t;

    if (i0 + 768 < total_v4) {
        // 4 sequential loads in flight, then shuffle+store each.
        const fvec4 a0 = x[i0 +   0];
        const fvec4 a1 = x[i0 + 256];
        const fvec4 a2 = x[i0 + 512];
        const fvec4 a3 = x[i0 + 768];
        out[i0 +   0] = lane_gather(a0, bp) - lane_gather(a0, bn);
        out[i0 + 256] = lane_gather(a1, bp) - lane_gather(a1, bn);
        out[i0 + 512] = lane_gather(a2, bp) - lane_gather(a2, bn);
        out[i0 + 768] = lane_gather(a3, bp) - lane_gather(a3, bn);
    } else {
        // Tail: total_v4 is a multiple of 64, so each wave-position's guard
        // is wave-uniform (bpermute sees all lanes active or none).
        #pragma unroll
        for (int j = 0; j < 4; ++j) {
            const int i = i0 + 256 * j;
            if (i < total_v4) {
                const fvec4 a = x[i];
                out[i] = lane_gather(a, bp) - lane_gather(a, bn);
            }
        }
    }
}

extern "C" void kernel_launch(void* const* d_in, const int* in_sizes, int n_in,
                              void* d_out, int out_size, void* d_ws, size_t ws_size,
                              hipStream_t stream)
{
    const fvec4* x    = (const fvec4*)d_in[0];
    const float* Ppos = (const float*)d_in[1];
    const float* Pneg = (const float*)d_in[2];
    fvec4*       out  = (fvec4*)d_out;

    const int total_v4 = out_size / 4;   // 33,554,432 / 4 = 8,388,608

    const int block = 256;
    // Each block covers 1024 float4 (16 rows, 4 per thread): 8192 blocks.
    const int grid = (total_v4 + 1023) / 1024;

    permute_ws_kernel<<<grid, block, 0, stream>>>(x, Ppos, Pneg, out, total_v4);
}